// Round 1
// baseline (672.445 us; speedup 1.0000x reference)
//
#include <hip/hip_runtime.h>

// FFT-conv: y = real(ifft2( sum_i K[o,i] * fft2(x[b,i]) )) + bias
// B=32, CIN=64, COUT=128, H=W=56.
// Exploits Hermitian symmetry: only rows kh=0..28 of the spectrum are
// computed/stored; inverse transform folds the conjugate half analytically.

#define HH 56
#define NF 3136      // 56*56
#define KH 29        // stored spectral rows
#define NFH 1624     // 29*56
constexpr int B = 32, CIN = 64, COUT = 128;
constexpr float PI2 = 6.283185307179586f;

// ---------------------------------------------------------------------------
// Kernel A: per-image forward FFT2 (via two 56-point DFT passes through LDS),
// emitting only rows kh < 29.  grid = B*CIN images.
__global__ __launch_bounds__(256) void kfwd(const float* __restrict__ x,
                                            float2* __restrict__ Xf) {
    __shared__ float  xs[NF];       // input image
    __shared__ float2 s1[NF];       // after row (w) DFT: s1[h][kw]
    __shared__ float2 tw[HH];       // e^{-2*pi*i*m/56}

    const int img = blockIdx.x;
    const int tid = threadIdx.x;

    if (tid < HH) {
        float s, c;
        __sincosf(-PI2 * (float)tid / 56.0f, &s, &c);
        tw[tid] = make_float2(c, s);
    }
    const float* xp = x + (size_t)img * NF;
    for (int idx = tid; idx < NF; idx += 256) xs[idx] = xp[idx];
    __syncthreads();

    // stage 1: DFT over w.  s1[h][k] = sum_w xs[h][w] * tw[(k*w)%56]
    for (int idx = tid; idx < NF; idx += 256) {
        const int h = idx / HH, k = idx % HH;
        const float* row = xs + h * HH;
        float ar = 0.f, ai = 0.f;
        int m = 0;
        #pragma unroll 8
        for (int w = 0; w < HH; ++w) {
            const float v = row[w];
            const float2 t = tw[m];
            ar += v * t.x;
            ai += v * t.y;
            m += k; if (m >= HH) m -= HH;
        }
        s1[idx] = make_float2(ar, ai);
    }
    __syncthreads();

    // stage 2: DFT over h, rows kh<29 only.
    float2* op = Xf + (size_t)img * NFH;
    for (int idx = tid; idx < NFH; idx += 256) {
        const int kh = idx / HH, kw = idx % HH;
        float ar = 0.f, ai = 0.f;
        int m = 0;
        #pragma unroll 8
        for (int h = 0; h < HH; ++h) {
            const float2 v = s1[h * HH + kw];
            const float2 t = tw[m];
            ar += v.x * t.x - v.y * t.y;
            ai += v.x * t.y + v.y * t.x;
            m += kh; if (m >= HH) m -= HH;
        }
        op[idx] = make_float2(ar, ai);
    }
}

// ---------------------------------------------------------------------------
// Kernel B: per-bin channel mix.  Y[b,o,f] = sum_i X[b,i,f] * K[o,i,f]
// (complex).  Block tile: 4 bins x 64 o x all 32 b; thread tile 4b x 8o.
__global__ __launch_bounds__(256) void kmix(const float2* __restrict__ Xf,
                                            const float* __restrict__ Kr,
                                            const float* __restrict__ Ki,
                                            float2* __restrict__ Yf) {
    __shared__ float2 Xs[B][5];     // [b][f] (+1 pad)
    __shared__ float  Krs[64][5];   // [o][f]
    __shared__ float  Kis[64][5];

    const int f0 = blockIdx.x * 4;
    const int o0 = blockIdx.y * 64;
    const int tid = threadIdx.x;
    const int fs = tid & 3;          // bin within tile
    const int bg = (tid >> 2) & 7;   // b-group: b = bg*4 + j
    const int og = tid >> 5;         // o-group: o = o0 + og*8 + k

    float accr[4][8] = {}, acci[4][8] = {};

    for (int i = 0; i < CIN; ++i) {
        __syncthreads();
        if (tid < 128) {
            const int b = tid >> 2, f = tid & 3;
            Xs[b][f] = Xf[(size_t)(b * CIN + i) * NFH + f0 + f];
        }
        {
            const int o = tid >> 2, f = tid & 3;
            const size_t kidx = (size_t)((o0 + o) * CIN + i) * NF + f0 + f;
            Krs[o][f] = Kr[kidx];
            Kis[o][f] = Ki[kidx];
        }
        __syncthreads();

        float xr[4], xi[4];
        #pragma unroll
        for (int j = 0; j < 4; ++j) {
            const float2 v = Xs[bg * 4 + j][fs];
            xr[j] = v.x; xi[j] = v.y;
        }
        #pragma unroll
        for (int k = 0; k < 8; ++k) {
            const float kr = Krs[og * 8 + k][fs];
            const float ki = Kis[og * 8 + k][fs];
            #pragma unroll
            for (int j = 0; j < 4; ++j) {
                accr[j][k] += xr[j] * kr - xi[j] * ki;
                acci[j][k] += xr[j] * ki + xi[j] * kr;
            }
        }
    }

    #pragma unroll
    for (int j = 0; j < 4; ++j) {
        const int b = bg * 4 + j;
        #pragma unroll
        for (int k = 0; k < 8; ++k) {
            const int o = o0 + og * 8 + k;
            Yf[(size_t)(b * COUT + o) * NFH + f0 + fs] =
                make_float2(accr[j][k], acci[j][k]);
        }
    }
}

// ---------------------------------------------------------------------------
// Kernel C: per-image inverse FFT2 from 29 stored rows + conjugate fold,
// real output + bias.  grid = B*COUT images.
__global__ __launch_bounds__(256) void kinv(const float2* __restrict__ Yf,
                                            const float* __restrict__ bias,
                                            float* __restrict__ out) {
    __shared__ float2 ys[NFH];      // loaded spectrum rows
    __shared__ float2 zs[NFH];      // after inverse-w pass: zs[kh][w]
    __shared__ float2 tw[HH];       // e^{+2*pi*i*m/56}

    const int img = blockIdx.x;     // b*COUT + o
    const int tid = threadIdx.x;

    if (tid < HH) {
        float s, c;
        __sincosf(PI2 * (float)tid / 56.0f, &s, &c);
        tw[tid] = make_float2(c, s);
    }
    const float2* yp = Yf + (size_t)img * NFH;
    for (int idx = tid; idx < NFH; idx += 256) ys[idx] = yp[idx];
    __syncthreads();

    // stage 1: inverse DFT over w (full 56 outputs per stored row)
    for (int idx = tid; idx < NFH; idx += 256) {
        const int kh = idx / HH, w = idx % HH;
        const float2* row = ys + kh * HH;
        float ar = 0.f, ai = 0.f;
        int m = 0;
        #pragma unroll 8
        for (int kw = 0; kw < HH; ++kw) {
            const float2 v = row[kw];
            const float2 t = tw[m];
            ar += v.x * t.x - v.y * t.y;
            ai += v.x * t.y + v.y * t.x;
            m += w; if (m >= HH) m -= HH;
        }
        zs[idx] = make_float2(ar, ai);
    }
    __syncthreads();

    // stage 2: inverse DFT over h with conjugate fold -> real output.
    // y[h,w] = (Zr[0,w] + (-1)^h * Zr[28,w] + 2*sum_{k=1..27} Re(Z[k,w] e^{+i*2pi*k*h/56})) / 3136
    const float bv = bias[img & (COUT - 1)];
    float* op = out + (size_t)img * NF;
    for (int idx = tid; idx < NF; idx += 256) {
        const int h = idx / HH, w = idx % HH;
        float acc = 0.f;
        int m = 0;
        #pragma unroll
        for (int k = 1; k <= 27; ++k) {
            m += h; if (m >= HH) m -= HH;     // m = (k*h) % 56
            const float2 v = zs[k * HH + w];
            const float2 t = tw[m];
            acc += v.x * t.x - v.y * t.y;     // Re(Z * e^{+i th})
        }
        const float z28 = zs[28 * HH + w].x;
        const float r = zs[w].x + ((h & 1) ? -z28 : z28) + 2.0f * acc;
        op[idx] = r * (1.0f / 3136.0f) + bv;
    }
}

// ---------------------------------------------------------------------------
extern "C" void kernel_launch(void* const* d_in, const int* in_sizes, int n_in,
                              void* d_out, int out_size, void* d_ws, size_t ws_size,
                              hipStream_t stream) {
    const float* x    = (const float*)d_in[0];
    const float* Kr   = (const float*)d_in[1];
    const float* Ki   = (const float*)d_in[2];
    const float* bias = (const float*)d_in[3];

    float2* Xf = (float2*)d_ws;                      // [B][CIN][1624]  26.6 MB
    float2* Yf = Xf + (size_t)B * CIN * NFH;         // [B][COUT][1624] 53.2 MB

    hipLaunchKernelGGL(kfwd, dim3(B * CIN), dim3(256), 0, stream, x, Xf);
    hipLaunchKernelGGL(kmix, dim3(NFH / 4, COUT / 64), dim3(256), 0, stream,
                       Xf, Kr, Ki, Yf);
    hipLaunchKernelGGL(kinv, dim3(B * COUT), dim3(256), 0, stream,
                       Yf, bias, (float*)d_out);
}

// Round 3
// 440.659 us; speedup vs baseline: 1.5260x; 1.5260x over previous
//
#include <hip/hip_runtime.h>

// FFT-conv: y = real(ifft2( sum_i K[o,i] * fft2(x[b,i]) )) + bias
// B=32, CIN=64, COUT=128, H=W=56.
// Hermitian symmetry: only spectral rows kh=0..28 stored.
// kfwd / kinv: 56-pt DFT passes expressed as bf16 MFMA GEMMs (pad 56->64,
// zero-padded twiddle matrices absorb padding; DFT matrices are symmetric so
// one row-major copy serves both A- and B-operand fragment reads).

#define HH 56
#define NF 3136      // 56*56
#define KH 29        // stored spectral rows
#define NFH 1624     // 29*56
constexpr int B = 32, CIN = 64, COUT = 128;
constexpr float PI2 = 6.283185307179586f;

typedef __attribute__((ext_vector_type(8))) short s8v;   // 8 x bf16 (A/B frag)
typedef __attribute__((ext_vector_type(4))) float f4v;   // C/D frag

#define MFMA(a, b, c) __builtin_amdgcn_mfma_f32_16x16x32_bf16(a, b, c, 0, 0, 0)

__device__ __host__ inline short f2bf(float f) {
    unsigned u = __builtin_bit_cast(unsigned, f);
    u += 0x7fffu + ((u >> 16) & 1u);      // round-to-nearest-even
    return (short)(u >> 16);
}

// ---------------------------------------------------------------------------
// Constant pool in d_ws (shorts):
//   Cw  [64][72] @0     : cos(2*pi*m*n/56), m<56&&n<56 else 0   (symmetric)
//   Sw  [64][72] @4608  : +sin(...)                             (symmetric)
//   SwN [64][72] @9216  : -sin(...)
//   A2C [64][40] @13824 : wgt(kh)*cos(2*pi*h*kh/56)/3136  (h<56,kh<29 else 0)
//   A2S [64][40] @16384 : -wgt(kh)*sin(...)/3136
__global__ __launch_bounds__(256) void ksetup(short* __restrict__ cpool) {
    int i = blockIdx.x * 256 + threadIdx.x;
    if (i < 4608) {
        int m = i / 72, n = i % 72;
        float c = 0.f, s = 0.f;
        if (m < 56 && n < 56) {
            float ang = PI2 * (float)((m * n) % 56) / 56.f;
            c = cosf(ang); s = sinf(ang);
        }
        cpool[i]        = f2bf(c);
        cpool[4608 + i] = f2bf(s);
        cpool[9216 + i] = f2bf(-s);
    } else if (i < 7168) {
        int j = i - 4608;
        int h = j / 40, kh = j % 40;
        float c = 0.f, s = 0.f;
        if (h < 56 && kh < 29) {
            float w = (kh == 0 || kh == 28) ? 1.f : 2.f;
            float ang = PI2 * (float)((h * kh) % 56) / 56.f;
            float sc = w * (1.f / 3136.f);
            c = sc * cosf(ang);
            s = -sc * sinf(ang);
        }
        cpool[13824 + j] = f2bf(c);
        cpool[16384 + j] = f2bf(s);
    }
}

// ---------------------------------------------------------------------------
// Kernel A: forward FFT2 per (b,i) image via two MFMA GEMM passes.
//   stage1: S1[h][kw]  = sum_w  x[h][w] * e^{-2pi i w kw/56}
//   stage2: X[kh][kw]  = sum_h  e^{-2pi i h kh/56} * S1[h][kw]   (kh<29 stored)
__global__ __launch_bounds__(256) void kfwd(const float* __restrict__ x,
                                            const short* __restrict__ cpool,
                                            float2* __restrict__ Xf) {
    __shared__ __align__(16) short Cw[4608], Sw[4608], SwN[4608];
    __shared__ __align__(16) short xs[4608];            // [h][72] bf16
    __shared__ __align__(16) short T1r[4608], T1i[4608]; // S1 transposed [kw][72]
    const int tid = threadIdx.x;
    {
        const int4* src = (const int4*)cpool;
        for (int i = tid; i < 576; i += 256) {
            ((int4*)Cw)[i]  = src[i];
            ((int4*)Sw)[i]  = src[576 + i];
            ((int4*)SwN)[i] = src[1152 + i];
        }
    }
    for (int i = tid; i < 2304; i += 256) ((int*)xs)[i] = 0;   // FIX: full 4608 shorts
    __syncthreads();
    const float* xp = x + (size_t)blockIdx.x * NF;
    for (int i = tid; i < NF; i += 256) {
        int h = i / 56, w = i % 56;
        xs[h * 72 + w] = f2bf(xp[i]);
    }
    __syncthreads();

    const int lane = tid & 63;
    const int nt = tid >> 6;            // wave = N-tile strip
    const int q = lane >> 4, l15 = lane & 15;

    // ---- stage 1: A = xs[h][w], B = (C - iS)[w][kw]  (B read via symmetry)
    f4v aR[4] = {}, aI[4] = {};
    for (int ks = 0; ks < 2; ++ks) {
        const int bo = (nt * 16 + l15) * 72 + ks * 32 + q * 8;
        s8v bC = *(const s8v*)&Cw[bo];
        s8v bS = *(const s8v*)&SwN[bo];
        for (int mt = 0; mt < 4; ++mt) {
            s8v a = *(const s8v*)&xs[(mt * 16 + l15) * 72 + ks * 32 + q * 8];
            aR[mt] = MFMA(a, bC, aR[mt]);
            aI[mt] = MFMA(a, bS, aI[mt]);
        }
    }
    for (int mt = 0; mt < 4; ++mt)
        for (int r = 0; r < 4; ++r) {
            int o = (nt * 16 + l15) * 72 + mt * 16 + q * 4 + r;  // [kw][h]
            T1r[o] = f2bf(aR[mt][r]);
            T1i[o] = f2bf(aI[mt][r]);
        }
    __syncthreads();

    // ---- stage 2: A = (C2|S2)[kh][h] (top 32 rows of Cw/Sw), B = S1[h][kw]
    //      Xr = C2*S1r + S2*S1i ;  Xi = C2*S1i - S2*S1r
    f4v xr[2] = {}, xi2[2] = {};
    for (int ks = 0; ks < 2; ++ks) {
        const int bo = (nt * 16 + l15) * 72 + ks * 32 + q * 8;
        s8v br = *(const s8v*)&T1r[bo];
        s8v bi = *(const s8v*)&T1i[bo];
        for (int mt = 0; mt < 2; ++mt) {
            const int ao = (mt * 16 + l15) * 72 + ks * 32 + q * 8;
            s8v aC  = *(const s8v*)&Cw[ao];
            s8v aS  = *(const s8v*)&Sw[ao];
            s8v aSN = *(const s8v*)&SwN[ao];
            xr[mt]  = MFMA(aC, br, xr[mt]);
            xr[mt]  = MFMA(aS, bi, xr[mt]);
            xi2[mt] = MFMA(aC, bi, xi2[mt]);
            xi2[mt] = MFMA(aSN, br, xi2[mt]);
        }
    }
    float2* op = Xf + (size_t)blockIdx.x * NFH;
    const int kw = nt * 16 + l15;
    if (kw < 56) {
        for (int mt = 0; mt < 2; ++mt)
            for (int r = 0; r < 4; ++r) {
                int kh = mt * 16 + q * 4 + r;
                if (kh < 29) op[kh * 56 + kw] = make_float2(xr[mt][r], xi2[mt][r]);
            }
    }
}

// ---------------------------------------------------------------------------
// Kernel B: per-bin channel mix (unchanged fp32 VALU this round).
__global__ __launch_bounds__(256) void kmix(const float2* __restrict__ Xf,
                                            const float* __restrict__ Kr,
                                            const float* __restrict__ Ki,
                                            float2* __restrict__ Yf) {
    __shared__ float2 Xs[B][5];
    __shared__ float  Krs[64][5];
    __shared__ float  Kis[64][5];

    const int f0 = blockIdx.x * 4;
    const int o0 = blockIdx.y * 64;
    const int tid = threadIdx.x;
    const int fs = tid & 3;
    const int bg = (tid >> 2) & 7;
    const int og = tid >> 5;

    float accr[4][8] = {}, acci[4][8] = {};

    for (int i = 0; i < CIN; ++i) {
        __syncthreads();
        if (tid < 128) {
            const int b = tid >> 2, f = tid & 3;
            Xs[b][f] = Xf[(size_t)(b * CIN + i) * NFH + f0 + f];
        }
        {
            const int o = tid >> 2, f = tid & 3;
            const size_t kidx = (size_t)((o0 + o) * CIN + i) * NF + f0 + f;
            Krs[o][f] = Kr[kidx];
            Kis[o][f] = Ki[kidx];
        }
        __syncthreads();

        float xr[4], xi[4];
        #pragma unroll
        for (int j = 0; j < 4; ++j) {
            const float2 v = Xs[bg * 4 + j][fs];
            xr[j] = v.x; xi[j] = v.y;
        }
        #pragma unroll
        for (int k = 0; k < 8; ++k) {
            const float kr = Krs[og * 8 + k][fs];
            const float ki = Kis[og * 8 + k][fs];
            #pragma unroll
            for (int j = 0; j < 4; ++j) {
                accr[j][k] += xr[j] * kr - xi[j] * ki;
                acci[j][k] += xr[j] * ki + xi[j] * kr;
            }
        }
    }

    #pragma unroll
    for (int j = 0; j < 4; ++j) {
        const int b = bg * 4 + j;
        #pragma unroll
        for (int k = 0; k < 8; ++k) {
            const int o = o0 + og * 8 + k;
            Yf[(size_t)(b * COUT + o) * NFH + f0 + fs] =
                make_float2(accr[j][k], acci[j][k]);
        }
    }
}

// ---------------------------------------------------------------------------
// Kernel C: inverse FFT2 per (b,o) image via two MFMA GEMM passes + fold.
//   inv1: Z[kh][w] = sum_kw Y[kh][kw] * e^{+2pi i kw w/56}
//   inv2: y[h][w]  = sum_kh wgt(kh)*(Zr*cos - Zi*sin)/3136 + bias
__global__ __launch_bounds__(256) void kinv(const float2* __restrict__ Yf,
                                            const short* __restrict__ cpool,
                                            const float* __restrict__ bias,
                                            float* __restrict__ out) {
    __shared__ __align__(16) short Cw[4608], Sw[4608], SwN[4608];
    __shared__ __align__(16) short A2C[2560], A2S[2560];
    __shared__ __align__(16) short Yr[2304], Yi[2304];   // [kh][72]
    __shared__ __align__(16) short ZTr[2560], ZTi[2560]; // Z transposed [w][40]
    const int tid = threadIdx.x;
    {
        const int4* src = (const int4*)cpool;
        for (int i = tid; i < 576; i += 256) {
            ((int4*)Cw)[i]  = src[i];
            ((int4*)Sw)[i]  = src[576 + i];
            ((int4*)SwN)[i] = src[1152 + i];
        }
        for (int i = tid; i < 320; i += 256) {
            ((int4*)A2C)[i] = src[1728 + i];
            ((int4*)A2S)[i] = src[2048 + i];
        }
    }
    for (int i = tid; i < 1152; i += 256) { ((int*)Yr)[i] = 0; ((int*)Yi)[i] = 0; }  // FIX: full arrays
    __syncthreads();
    const float2* yp = Yf + (size_t)blockIdx.x * NFH;
    for (int f = tid; f < NFH; f += 256) {
        int kh = f / 56, kw = f % 56;
        float2 v = yp[f];
        Yr[kh * 72 + kw] = f2bf(v.x);
        Yi[kh * 72 + kw] = f2bf(v.y);
    }
    __syncthreads();

    const int lane = tid & 63;
    const int nt = tid >> 6;
    const int q = lane >> 4, l15 = lane & 15;

    // ---- inv1: A = Y[kh][kw], B = (C + iS)[kw][w] via symmetry
    //      Zr = Yr*C - Yi*S ;  Zi = Yr*S + Yi*C
    f4v zr[2] = {}, zi[2] = {};
    for (int ks = 0; ks < 2; ++ks) {
        const int bo = (nt * 16 + l15) * 72 + ks * 32 + q * 8;
        s8v bC  = *(const s8v*)&Cw[bo];
        s8v bS  = *(const s8v*)&Sw[bo];
        s8v bSN = *(const s8v*)&SwN[bo];
        for (int mt = 0; mt < 2; ++mt) {
            const int ao = (mt * 16 + l15) * 72 + ks * 32 + q * 8;
            s8v ar = *(const s8v*)&Yr[ao];
            s8v ai = *(const s8v*)&Yi[ao];
            zr[mt] = MFMA(ar, bC, zr[mt]);
            zr[mt] = MFMA(ai, bSN, zr[mt]);
            zi[mt] = MFMA(ar, bS, zi[mt]);
            zi[mt] = MFMA(ai, bC, zi[mt]);
        }
    }
    for (int mt = 0; mt < 2; ++mt)
        for (int r = 0; r < 4; ++r) {
            int o = (nt * 16 + l15) * 40 + mt * 16 + q * 4 + r;  // [w][kh]
            ZTr[o] = f2bf(zr[mt][r]);
            ZTi[o] = f2bf(zi[mt][r]);
        }
    __syncthreads();

    // ---- inv2: A = A2C/A2S [h][kh] (K=32, one k-step), B = Z[kh][w]
    f4v yv[4] = {};
    {
        const int bo = (nt * 16 + l15) * 40 + q * 8;
        s8v br = *(const s8v*)&ZTr[bo];
        s8v bi = *(const s8v*)&ZTi[bo];
        for (int mt = 0; mt < 4; ++mt) {
            const int ao = (mt * 16 + l15) * 40 + q * 8;
            s8v ac  = *(const s8v*)&A2C[ao];
            s8v as_ = *(const s8v*)&A2S[ao];
            yv[mt] = MFMA(ac, br, yv[mt]);
            yv[mt] = MFMA(as_, bi, yv[mt]);
        }
    }
    const float bv = bias[blockIdx.x & (COUT - 1)];
    float* opx = out + (size_t)blockIdx.x * NF;
    const int w = nt * 16 + l15;
    if (w < 56) {
        for (int mt = 0; mt < 4; ++mt)
            for (int r = 0; r < 4; ++r) {
                int h = mt * 16 + q * 4 + r;
                if (h < 56) opx[h * 56 + w] = yv[mt][r] + bv;
            }
    }
}

// ---------------------------------------------------------------------------
extern "C" void kernel_launch(void* const* d_in, const int* in_sizes, int n_in,
                              void* d_out, int out_size, void* d_ws, size_t ws_size,
                              hipStream_t stream) {
    const float* x    = (const float*)d_in[0];
    const float* Kr   = (const float*)d_in[1];
    const float* Ki   = (const float*)d_in[2];
    const float* bias = (const float*)d_in[3];

    short*  cpool = (short*)d_ws;                    // 37888 B constants
    float2* Xf = (float2*)((char*)d_ws + 40960);     // [B][CIN][1624]  26.6 MB
    float2* Yf = Xf + (size_t)B * CIN * NFH;         // [B][COUT][1624] 53.2 MB

    hipLaunchKernelGGL(ksetup, dim3(28), dim3(256), 0, stream, cpool);
    hipLaunchKernelGGL(kfwd, dim3(B * CIN), dim3(256), 0, stream, x, cpool, Xf);
    hipLaunchKernelGGL(kmix, dim3(NFH / 4, COUT / 64), dim3(256), 0, stream,
                       Xf, Kr, Ki, Yf);
    hipLaunchKernelGGL(kinv, dim3(B * COUT), dim3(256), 0, stream,
                       Yf, cpool, bias, (float*)d_out);
}